// Round 13
// baseline (123.895 us; speedup 1.0000x reference)
//
#include <hip/hip_runtime.h>
#include <math.h>

// Problem constants (fixed by setup_inputs): B=8, C=32, H=256, W=256, step=32.
#define BB 8
#define CC 32
#define HH 256
#define WW 256

// ---------------------------------------------------------------------------
// Kernel 1: rden(b,h,i) = 1 / sum_t g_t * w[b,0,h,src_t(i)]  -> d_ws (8 MB)
// One block per (b,h); thread i gathers 12 w values (1 KB row, L1-resident).
// ---------------------------------------------------------------------------
__global__ __launch_bounds__(256)
void den_kernel(const float* __restrict__ s,
                const float* __restrict__ wg,
                const float* __restrict__ w_param,
                const float* __restrict__ b_param,
                float* __restrict__ rden_out) {
    const int bh = blockIdx.x;              // b*HH + h
    const int b  = bh >> 8;
    const int i  = threadIdx.x;

    const float* wrow = wg + (size_t)bh * WW;
    const float wp = w_param[0], bpv = b_param[0];
    float g[11];
    #pragma unroll
    for (int k = 0; k < 11; ++k)
        g[k] = 1.0f / (1.0f + __expf(-(wp * s[b * 11 + k] + bpv)));

    float den = wrow[i];                                  // identity term
    #pragma unroll
    for (int k = 1; k <= 7; ++k)                          // shifts
        den = fmaf(g[k - 1], wrow[(i - 32 * k) & (WW - 1)], den);
    #pragma unroll
    for (int j = 0; j < 4; ++j)                           // flips about 32j+31
        den = fmaf(g[7 + j], wrow[(32 * j + 31 - i) & (WW - 1)], den);

    rden_out[(size_t)bh * WW + i] = __builtin_amdgcn_rcpf(den);
}

// ---------------------------------------------------------------------------
// Main kernel. Position i = 32*q + 4*u + e.
//   roll by 32k:       q -> (q-k)&7, u,e unchanged        (register index)
//   flip about 32j+31: q -> (j-q)&7, u -> 7-u, e -> 3-e   (DPP row_half_mirror)
// Lane l = 8*row + u; wave = 8 channel-rows x 8 u-lanes. Zero LDS, zero
// barriers. Denominator comes precomputed from d_ws.
// ---------------------------------------------------------------------------
__device__ __forceinline__ float half_mirror(float v) {
    int i = __builtin_bit_cast(int, v);
    i = __builtin_amdgcn_update_dpp(i, i, 0x141, 0xf, 0xf, true); // row_half_mirror
    return __builtin_bit_cast(float, i);
}

__global__ __launch_bounds__(256, 4)
void symctrl2_main(const float* __restrict__ x,
                   const float* __restrict__ s,
                   const float* __restrict__ wg,
                   const float* __restrict__ w_param,
                   const float* __restrict__ b_param,
                   const float* __restrict__ rden,
                   float* __restrict__ out) {
    const int bh  = blockIdx.x;             // one block per (b,h)
    const int b   = bh >> 8;
    const int wv  = threadIdx.x >> 6;       // wave 0..3 -> channels 8wv..8wv+7
    const int l   = threadIdx.x & 63;
    const int row = l >> 3;
    const int u   = l & 7;
    const int c   = (wv << 3) + row;

    const float* wrow = wg   + (size_t)bh * WW;
    const float* rrow = rden + (size_t)bh * WW;
    const size_t xoff = (((size_t)b * CC + c) * HH + (bh & (HH - 1))) * WW;
    const float* xrow = x + xoff;
    float*       orow = out + xoff;

    // ---- issue w and x loads up front ----
    float4 wq[8], xq[8];
    #pragma unroll
    for (int q = 0; q < 8; ++q)
        wq[q] = *reinterpret_cast<const float4*>(wrow + 32 * q + 4 * u);
    #pragma unroll
    for (int q = 0; q < 8; ++q)
        xq[q] = *reinterpret_cast<const float4*>(xrow + 32 * q + 4 * u);

    // ---- gates (uniform per b; cheap, hides under load latency) ----
    const float wp = w_param[0], bpv = b_param[0];
    float gk[8], gf[4];
    gk[0] = 1.0f;
    #pragma unroll
    for (int k = 0; k < 7; ++k)
        gk[k + 1] = 1.0f / (1.0f + __expf(-(wp * s[b * 11 + k] + bpv)));
    #pragma unroll
    for (int j = 0; j < 4; ++j)
        gf[j] = 1.0f / (1.0f + __expf(-(wp * s[b * 11 + 7 + j] + bpv)));

    // ---- P = w*x; wq/xq die here, keeping peak VGPR pressure low ----
    float P[8][4];
    #pragma unroll
    for (int q = 0; q < 8; ++q) {
        P[q][0] = wq[q].x * xq[q].x;
        P[q][1] = wq[q].y * xq[q].y;
        P[q][2] = wq[q].z * xq[q].z;
        P[q][3] = wq[q].w * xq[q].w;
    }
    asm volatile("" ::: "memory");          // keep rden loads below P formation

    // ---- rden loads; ~800 cyc of num compute below hides their latency ----
    float4 rq[8];
    #pragma unroll
    for (int g = 0; g < 8; ++g)
        rq[g] = *reinterpret_cast<const float4*>(rrow + 32 * g + 4 * u);

    // ---- numerator: shift part (circular correlation over q) ----
    float num[8][4];
    #pragma unroll
    for (int g = 0; g < 8; ++g) {
        float n0 = 0.f, n1 = 0.f, n2 = 0.f, n3 = 0.f;
        #pragma unroll
        for (int k = 0; k < 8; ++k) {
            const int q = (g - k) & 7;
            n0 = fmaf(gk[k], P[q][0], n0);
            n1 = fmaf(gk[k], P[q][1], n1);
            n2 = fmaf(gk[k], P[q][2], n2);
            n3 = fmaf(gk[k], P[q][3], n3);
        }
        num[g][0] = n0; num[g][1] = n1; num[g][2] = n2; num[g][3] = n3;
    }
    // ---- numerator: flip part via DPP mirror of P ----
    #pragma unroll
    for (int q = 0; q < 8; ++q) {
        const float m0 = half_mirror(P[q][0]);
        const float m1 = half_mirror(P[q][1]);
        const float m2 = half_mirror(P[q][2]);
        const float m3 = half_mirror(P[q][3]);
        #pragma unroll
        for (int j = 0; j < 4; ++j) {
            const int g = (j - q) & 7;
            num[g][0] = fmaf(gf[j], m3, num[g][0]);   // e reversed: 3-e
            num[g][1] = fmaf(gf[j], m2, num[g][1]);
            num[g][2] = fmaf(gf[j], m1, num[g][2]);
            num[g][3] = fmaf(gf[j], m0, num[g][3]);
        }
    }
    // ---- scale and store ----
    #pragma unroll
    for (int g = 0; g < 8; ++g) {
        float4 o;
        o.x = num[g][0] * rq[g].x;
        o.y = num[g][1] * rq[g].y;
        o.z = num[g][2] * rq[g].z;
        o.w = num[g][3] * rq[g].w;
        *reinterpret_cast<float4*>(orow + 32 * g + 4 * u) = o;
    }
}

extern "C" void kernel_launch(void* const* d_in, const int* in_sizes, int n_in,
                              void* d_out, int out_size, void* d_ws, size_t ws_size,
                              hipStream_t stream) {
    const float* x  = (const float*)d_in[0];
    const float* s  = (const float*)d_in[1];
    const float* w  = (const float*)d_in[2];
    const float* wp = (const float*)d_in[3];
    const float* bp = (const float*)d_in[4];
    float* outp = (float*)d_out;
    float* rden = (float*)d_ws;             // BB*HH*WW floats = 8 MB scratch

    dim3 grid(BB * HH);                     // 2048 blocks, one per (b,h)
    den_kernel<<<grid, dim3(WW), 0, stream>>>(s, w, wp, bp, rden);
    symctrl2_main<<<grid, dim3(256), 0, stream>>>(x, s, w, wp, bp, rden, outp);
}